// Round 8
// baseline (281.022 us; speedup 1.0000x reference)
//
#include <hip/hip_runtime.h>

#define BB 16
#define CC 256
#define HW 9216   // 96*96

typedef short bf16x8 __attribute__((ext_vector_type(8)));
typedef float f32x4 __attribute__((ext_vector_type(4)));

__device__ __forceinline__ unsigned short f2bf(float f) {
  unsigned u = __float_as_uint(f);
  return (unsigned short)((u + 0x7FFFu + ((u >> 16) & 1u)) >> 16);
}
__device__ __forceinline__ float bf2f(unsigned short h) {
  return __uint_as_float(((unsigned)h) << 16);
}

// ---------------- K1: adaptive avg pool 96x96 -> 8x8 per (b,c) plane ----------------
__global__ __launch_bounds__(256) void k_pool(const float* __restrict__ x,
                                              float* __restrict__ pooled) {
  int bc = blockIdx.x;
  const float* plane = x + (size_t)bc * HW;
  __shared__ float rowwin[96][8];
  for (int idx = threadIdx.x; idx < 96 * 8; idx += 256) {
    int y = idx >> 3, wx = idx & 7;
    const float* r = plane + y * 96 + wx * 12;
    float s = 0.f;
#pragma unroll
    for (int i = 0; i < 12; ++i) s += r[i];
    rowwin[y][wx] = s;
  }
  __syncthreads();
  if (threadIdx.x < 64) {
    int wy = threadIdx.x >> 3, wx = threadIdx.x & 7;
    float s = 0.f;
#pragma unroll
    for (int i = 0; i < 12; ++i) s += rowwin[wy * 12 + i][wx];
    pooled[(size_t)bc * 64 + threadIdx.x] = s * (1.0f / 144.0f);
  }
}

// ---------------- K2: inverse L2 norm over channels of pooled, per (b,p) ----------------
__global__ __launch_bounds__(256) void k_invn(const float* __restrict__ pooled,
                                              float* __restrict__ invn) {
  int b = blockIdx.x;
  int p = threadIdx.x & 63, cg = threadIdx.x >> 6;
  const float* pb = pooled + (size_t)b * CC * 64;
  float s = 0.f;
  for (int c = cg; c < CC; c += 4) { float v = pb[c * 64 + p]; s += v * v; }
  __shared__ float sm[4][64];
  sm[cg][p] = s;
  __syncthreads();
  if (threadIdx.x < 64) {
    float tot = sm[0][p] + sm[1][p] + sm[2][p] + sm[3][p];
    invn[b * 64 + p] = 1.0f / fmaxf(sqrtf(tot), 1e-12f);
  }
}

// ---------------- K3: Mbf[b][o][c] = bf16( sum_p W1[o][p] * ker[b][c][p] ) ----------------
__global__ __launch_bounds__(256) void k_M(const float* __restrict__ pooled,
                                           const float* __restrict__ invn,
                                           const float* __restrict__ W1,
                                           unsigned short* __restrict__ Mbf) {
  int c0 = blockIdx.x * 16, b = blockIdx.y, t = threadIdx.x;
  __shared__ float W1s[64][65];
  __shared__ float kers[16][65];
  __shared__ float invs[64];
  if (t < 64) invs[t] = invn[b * 64 + t];
  for (int i = t; i < 4096; i += 256) W1s[i >> 6][i & 63] = W1[i];
  __syncthreads();
  for (int i = t; i < 1024; i += 256) {
    int c = i >> 6, p = i & 63;
    kers[c][p] = pooled[((size_t)b * CC + c0 + c) * 64 + p] * invs[p];
  }
  __syncthreads();
  int c = t & 15, og = t >> 4;
  float s0 = 0.f, s1 = 0.f, s2 = 0.f, s3 = 0.f;
#pragma unroll
  for (int p = 0; p < 64; ++p) {
    float kv = kers[c][p];
    s0 = fmaf(W1s[og * 4 + 0][p], kv, s0);
    s1 = fmaf(W1s[og * 4 + 1][p], kv, s1);
    s2 = fmaf(W1s[og * 4 + 2][p], kv, s2);
    s3 = fmaf(W1s[og * 4 + 3][p], kv, s3);
  }
  unsigned short* Mb = Mbf + (size_t)b * 64 * 256 + c0 + c;
  Mb[(og * 4 + 0) * 256] = f2bf(s0);
  Mb[(og * 4 + 1) * 256] = f2bf(s1);
  Mb[(og * 4 + 2) * 256] = f2bf(s2);
  Mb[(og * 4 + 3) * 256] = f2bf(s3);
}

// ---------------- K4: prep: W3 -> bf16 [o][320], W2 -> bf16 [tap][o][f], zero stats ----------------
__global__ void k_prep(const float* __restrict__ W3, unsigned short* __restrict__ W3bf,
                       const float* __restrict__ W2, unsigned short* __restrict__ W2bf,
                       float* __restrict__ statsbuf) {
  int i = blockIdx.x * 256 + threadIdx.x;
  if (i < 64 * 320) W3bf[i] = f2bf(W3[i]);
  if (i < 9 * 64 * 64) {
    int tap = i >> 12, rem = i & 4095;
    int o = rem >> 6, f = rem & 63;
    W2bf[i] = f2bf(W2[(size_t)(o * 64 + f) * 9 + tap]);
  }
  if (i < 4096) statsbuf[i] = 0.f;
}

// ---------------- K5: fused transpose + gemm1 + y0: per (b, 64-px tile) ----------------
__global__ __launch_bounds__(256) void k_tg1(
    const float* __restrict__ x,
    const unsigned short* __restrict__ Mbf,
    const unsigned short* __restrict__ W3bf,
    const float* __restrict__ b1,
    unsigned short* __restrict__ hpix,
    float* __restrict__ y0,
    float* __restrict__ stats1) {
  int b = blockIdx.y;
  int px0 = blockIdx.x * 64;
  int t = threadIdx.x;
  int px = t & 63, cg = t >> 6;            // staging roles
  int w = t >> 6, lane = t & 63, l15 = lane & 15, l4 = lane >> 4;  // MFMA roles
  __shared__ unsigned char sm[32768];      // [64 px][256 c] bf16, 16B-granule swizzled
  __shared__ float sq[64];
  if (t < 64) sq[t] = 0.f;
  __syncthreads();
  // ---- stage ----
  float part = 0.f;
  const float* xb = x + (size_t)b * CC * HW + px0 + px;
#pragma unroll
  for (int kk = 0; kk < 8; ++kk) {
    int c = cg * 64 + kk * 8;
    float v[8];
#pragma unroll
    for (int j = 0; j < 8; ++j) {
      v[j] = xb[(size_t)(c + j) * HW];
      part += v[j] * v[j];
    }
    uint4 pk;
    pk.x = (unsigned)f2bf(v[0]) | ((unsigned)f2bf(v[1]) << 16);
    pk.y = (unsigned)f2bf(v[2]) | ((unsigned)f2bf(v[3]) << 16);
    pk.z = (unsigned)f2bf(v[4]) | ((unsigned)f2bf(v[5]) << 16);
    pk.w = (unsigned)f2bf(v[6]) | ((unsigned)f2bf(v[7]) << 16);
    int u = cg * 8 + kk;
    *(uint4*)(sm + px * 512 + ((u ^ (px & 31)) << 4)) = pk;
  }
  atomicAdd(&sq[px], part);
  __syncthreads();
  // ---- MFMA: wave w owns o-range [w*16, w*16+16) for both h and y0 ----
  f32x4 acch[4], accy[4];
#pragma unroll
  for (int nf = 0; nf < 4; ++nf) { f32x4 z = {0.f,0.f,0.f,0.f}; acch[nf] = z; accy[nf] = z; }
  const unsigned short* Ma = Mbf + ((size_t)b * 64 + w * 16 + l15) * 256;
  const unsigned short* Wa = W3bf + (size_t)(w * 16 + l15) * 320;
#pragma unroll
  for (int kk = 0; kk < 8; ++kk) {
    bf16x8 am = *(const bf16x8*)(Ma + kk * 32 + l4 * 8);
    bf16x8 aw = *(const bf16x8*)(Wa + kk * 32 + l4 * 8);
    int u = kk * 4 + l4;
#pragma unroll
    for (int nf = 0; nf < 4; ++nf) {
      int p2 = nf * 16 + l15;
      bf16x8 bfr = *(const bf16x8*)(sm + p2 * 512 + ((u ^ (p2 & 31)) << 4));
      acch[nf] = __builtin_amdgcn_mfma_f32_16x16x32_bf16(am, bfr, acch[nf], 0, 0, 0);
      accy[nf] = __builtin_amdgcn_mfma_f32_16x16x32_bf16(aw, bfr, accy[nf], 0, 0, 0);
    }
  }
  // ---- epilogue ----
  float inv[4];
#pragma unroll
  for (int nf = 0; nf < 4; ++nf)
    inv[nf] = 1.0f / fmaxf(sqrtf(sq[nf * 16 + l15]), 1e-12f);
  float b1v[4];
#pragma unroll
  for (int i = 0; i < 4; ++i) b1v[i] = b1[w * 16 + l4 * 4 + i];
  float s_acc[4], ss_acc[4];
#pragma unroll
  for (int i = 0; i < 4; ++i) { s_acc[i] = 0.f; ss_acc[i] = 0.f; }
  __syncthreads();                          // all sm MFMA reads done; reuse as h epi tile
#pragma unroll
  for (int nf = 0; nf < 4; ++nf) {
    float hv[4];
#pragma unroll
    for (int i = 0; i < 4; ++i) {
      hv[i] = fmaf(acch[nf][i], inv[nf], b1v[i]);
      s_acc[i] += hv[i];
      ss_acc[i] += hv[i] * hv[i];
    }
    uint2 pk;
    pk.x = (unsigned)f2bf(hv[0]) | ((unsigned)f2bf(hv[1]) << 16);
    pk.y = (unsigned)f2bf(hv[2]) | ((unsigned)f2bf(hv[3]) << 16);
    int p2 = nf * 16 + l15;
    int v = w * 4 + l4;                     // 8B unit (4 o's) within 128B pixel row
    *(uint2*)(sm + p2 * 128 + ((v ^ ((p2 & 7) << 1)) << 3)) = pk;
#pragma unroll
    for (int i = 0; i < 4; ++i)
      y0[((size_t)(b * 64 + w * 16 + l4 * 4 + i)) * HW + px0 + nf * 16 + l15] = accy[nf][i];
  }
#pragma unroll
  for (int i = 0; i < 4; ++i) {
    float s = s_acc[i], q = ss_acc[i];
#pragma unroll
    for (int m = 1; m < 16; m <<= 1) {
      s += __shfl_xor(s, m);
      q += __shfl_xor(q, m);
    }
    if (l15 == 0) {
      int o = w * 16 + l4 * 4 + i;
      atomicAdd(&stats1[(b * 64 + o) * 2], s);
      atomicAdd(&stats1[(b * 64 + o) * 2 + 1], q);
    }
  }
  __syncthreads();
  uint4* dst = (uint4*)(hpix + ((size_t)b * HW + px0) * 64);
  for (int i = t; i < 512; i += 256) {
    int p = i >> 3, u16 = i & 7;
    dst[i] = *(const uint4*)(sm + p * 128 + ((u16 ^ (p & 7)) << 4));
  }
}

// ---------------- K6: fused conv3x3 + gemm2-lite, 2-row bands -> opre bf16 + stats2 ----------------
__global__ __launch_bounds__(256) void k_cg2(
    const unsigned short* __restrict__ hpix,
    const float* __restrict__ stats1,
    const unsigned short* __restrict__ W2bf,
    const float* __restrict__ b2,
    const float* __restrict__ y0,
    const unsigned short* __restrict__ W3bf,
    const float* __restrict__ b3,
    unsigned short* __restrict__ opre,
    float* __restrict__ stats2) {
  int band = blockIdx.x;              // 0..47 (2 output rows each)
  int b = blockIdx.y;
  int t = threadIdx.x;
  int w = t >> 6;
  int lane = t & 63;
  int l15 = lane & 15, l4 = lane >> 4;
  int wr = w >> 1;                    // wave's output row within band (0..1)
  int half = w & 1;                   // wave's 48-px half of the row

  __shared__ unsigned char smem[25088];  // conv stage 4*98*64B; reused as h/opre tile 192*128B
  __shared__ float scs[64], shs[64];
  if (t < 64) {
    float S = stats1[(b * 64 + t) * 2], SS = stats1[(b * 64 + t) * 2 + 1];
    float mean = S * (1.0f / (float)HW);
    float var = SS * (1.0f / (float)HW) - mean * mean;
    float rstd = rsqrtf(var + 1e-5f);
    scs[t] = rstd;
    shs[t] = -mean * rstd;
  }

  // ---- phase 1: conv3x3 MFMA (acc in registers) ----
  f32x4 acc[4][3];
#pragma unroll
  for (int mf = 0; mf < 4; ++mf)
#pragma unroll
    for (int nf = 0; nf < 3; ++nf) { f32x4 z = {0.f,0.f,0.f,0.f}; acc[mf][nf] = z; }

  for (int f0 = 0; f0 < 64; f0 += 32) {
    __syncthreads();
    for (int idx = t; idx < 4 * 98 * 8; idx += 256) {
      int f4 = idx & 7;
      int v = idx >> 3;
      int xr = v % 98;
      int r = v / 98;
      int gy = band * 2 - 1 + r;
      int gx = xr - 1;
      unsigned pk0 = 0, pk1 = 0;
      if ((unsigned)gy < 96u && (unsigned)gx < 96u) {
        const ushort4 rv = *(const ushort4*)(hpix +
            ((size_t)((size_t)b * HW + gy * 96 + gx) * 64 + f0 + f4 * 4));
        int fb = f0 + f4 * 4;
        float v0 = fmaxf(0.f, fmaf(bf2f(rv.x), scs[fb],     shs[fb]));
        float v1 = fmaxf(0.f, fmaf(bf2f(rv.y), scs[fb + 1], shs[fb + 1]));
        float v2 = fmaxf(0.f, fmaf(bf2f(rv.z), scs[fb + 2], shs[fb + 2]));
        float v3 = fmaxf(0.f, fmaf(bf2f(rv.w), scs[fb + 3], shs[fb + 3]));
        pk0 = (unsigned)f2bf(v0) | ((unsigned)f2bf(v1) << 16);
        pk1 = (unsigned)f2bf(v2) | ((unsigned)f2bf(v3) << 16);
      }
      int g = f4 >> 1;
      int gs = g ^ ((xr >> 1) & 3);
      unsigned loff = (unsigned)((r * 98 + xr) * 64 + gs * 16 + (f4 & 1) * 8);
      *(uint2*)(smem + loff) = make_uint2(pk0, pk1);
    }
    __syncthreads();
#pragma unroll
    for (int dy = 0; dy < 3; ++dy) {
      int r = wr + dy;
#pragma unroll
      for (int dx = 0; dx < 3; ++dx) {
        int tap = dy * 3 + dx;
        bf16x8 afr[4];
#pragma unroll
        for (int mf = 0; mf < 4; ++mf) {
          int o = mf * 16 + l15;
          afr[mf] = *(const bf16x8*)(W2bf + ((size_t)(tap * 64 + o) * 64 + f0 + l4 * 8));
        }
#pragma unroll
        for (int nf = 0; nf < 3; ++nf) {
          int xr = half * 48 + nf * 16 + l15 + dx;
          unsigned loff = (unsigned)((r * 98 + xr) * 64 + ((l4 ^ ((xr >> 1) & 3)) * 16));
          bf16x8 bfr = *(const bf16x8*)(smem + loff);
#pragma unroll
          for (int mf = 0; mf < 4; ++mf)
            acc[mf][nf] = __builtin_amdgcn_mfma_f32_16x16x32_bf16(
                afr[mf], bfr, acc[mf][nf], 0, 0, 0);
        }
      }
    }
  }
  // ---- phase 2: h(+b2) -> LDS tile [192 px][64 o] bf16 (swizzled 8B granules) ----
  float b2v[4][4];
#pragma unroll
  for (int mf = 0; mf < 4; ++mf)
#pragma unroll
    for (int i = 0; i < 4; ++i) b2v[mf][i] = b2[mf * 16 + l4 * 4 + i];
  __syncthreads();
#pragma unroll
  for (int mf = 0; mf < 4; ++mf)
#pragma unroll
    for (int nf = 0; nf < 3; ++nf) {
      int tpx = wr * 96 + half * 48 + nf * 16 + l15;
      float h0 = acc[mf][nf][0] + b2v[mf][0];
      float h1 = acc[mf][nf][1] + b2v[mf][1];
      float h2 = acc[mf][nf][2] + b2v[mf][2];
      float h3 = acc[mf][nf][3] + b2v[mf][3];
      uint2 pk;
      pk.x = (unsigned)f2bf(h0) | ((unsigned)f2bf(h1) << 16);
      pk.y = (unsigned)f2bf(h2) | ((unsigned)f2bf(h3) << 16);
      int v = mf * 4 + l4;
      *(uint2*)(smem + tpx * 128 + ((v ^ ((tpx & 7) << 1)) << 3)) = pk;
    }
  __syncthreads();
  // ---- phase 3: acc2 = y0 + W3[:,256:]·h ----
  f32x4 acc2[4][3];
#pragma unroll
  for (int mf = 0; mf < 4; ++mf)
#pragma unroll
    for (int i = 0; i < 4; ++i) {
      int o = mf * 16 + l4 * 4 + i;
      const float* yrow = y0 + ((size_t)b * 64 + o) * HW + band * 192 + wr * 96 + half * 48 + l15;
#pragma unroll
      for (int nf = 0; nf < 3; ++nf) acc2[mf][nf][i] = yrow[nf * 16];
    }
#pragma unroll
  for (int kk = 0; kk < 2; ++kk) {
    bf16x8 afr[4];
#pragma unroll
    for (int mf = 0; mf < 4; ++mf)
      afr[mf] = *(const bf16x8*)(W3bf + (size_t)(mf * 16 + l15) * 320 + 256 + kk * 32 + l4 * 8);
#pragma unroll
    for (int nf = 0; nf < 3; ++nf) {
      int tpx = wr * 96 + half * 48 + nf * 16 + l15;
      int v0 = kk * 8 + l4 * 2;
      union { bf16x8 v; uint2 h[2]; } bb;
      bb.h[0] = *(const uint2*)(smem + tpx * 128 + (((v0    ) ^ ((tpx & 7) << 1)) << 3));
      bb.h[1] = *(const uint2*)(smem + tpx * 128 + (((v0 + 1) ^ ((tpx & 7) << 1)) << 3));
#pragma unroll
      for (int mf = 0; mf < 4; ++mf)
        acc2[mf][nf] = __builtin_amdgcn_mfma_f32_16x16x32_bf16(afr[mf], bb.v, acc2[mf][nf], 0, 0, 0);
    }
  }
  // ---- stats2 over this block's 192 px ----
  float b3v[4][4];
#pragma unroll
  for (int mf = 0; mf < 4; ++mf)
#pragma unroll
    for (int i = 0; i < 4; ++i) b3v[mf][i] = b3[mf * 16 + l4 * 4 + i];
  float s_acc[4][4], ss_acc[4][4];
#pragma unroll
  for (int mf = 0; mf < 4; ++mf)
#pragma unroll
    for (int i = 0; i < 4; ++i) { s_acc[mf][i] = 0.f; ss_acc[mf][i] = 0.f; }
#pragma unroll
  for (int mf = 0; mf < 4; ++mf)
#pragma unroll
    for (int nf = 0; nf < 3; ++nf)
#pragma unroll
      for (int i = 0; i < 4; ++i) {
        float hv = acc2[mf][nf][i] + b3v[mf][i];
        s_acc[mf][i] += hv;
        ss_acc[mf][i] += hv * hv;
      }
#pragma unroll
  for (int mf = 0; mf < 4; ++mf)
#pragma unroll
    for (int i = 0; i < 4; ++i) {
      float s = s_acc[mf][i], q = ss_acc[mf][i];
#pragma unroll
      for (int m = 1; m < 16; m <<= 1) {
        s += __shfl_xor(s, m);
        q += __shfl_xor(q, m);
      }
      if (l15 == 0) {
        int o = mf * 16 + l4 * 4 + i;
        atomicAdd(&stats2[(b * 64 + o) * 2], s);
        atomicAdd(&stats2[(b * 64 + o) * 2 + 1], q);
      }
    }
  // ---- epilogue: opre bf16 pixel-major via LDS retile ----
  __syncthreads();                       // phase-3 smem reads done
#pragma unroll
  for (int mf = 0; mf < 4; ++mf)
#pragma unroll
    for (int nf = 0; nf < 3; ++nf) {
      int tpx = wr * 96 + half * 48 + nf * 16 + l15;
      float h0 = acc2[mf][nf][0] + b3v[mf][0];
      float h1 = acc2[mf][nf][1] + b3v[mf][1];
      float h2 = acc2[mf][nf][2] + b3v[mf][2];
      float h3 = acc2[mf][nf][3] + b3v[mf][3];
      uint2 pk;
      pk.x = (unsigned)f2bf(h0) | ((unsigned)f2bf(h1) << 16);
      pk.y = (unsigned)f2bf(h2) | ((unsigned)f2bf(h3) << 16);
      int v = mf * 4 + l4;
      *(uint2*)(smem + tpx * 128 + ((v ^ ((tpx & 7) << 1)) << 3)) = pk;
    }
  __syncthreads();
  uint4* dst = (uint4*)(opre + ((size_t)b * HW + band * 192) * 64);
  for (int i = t; i < 1536; i += 256) {
    int p = i >> 3, u16 = i & 7;
    dst[i] = *(const uint4*)(smem + p * 128 + ((u16 ^ (p & 7)) << 4));
  }
}

// ---------------- K7: apply IN+ReLU, transpose to o-major fp32 d_out ----------------
__global__ __launch_bounds__(256) void k_apply(const unsigned short* __restrict__ opre,
                                               const float* __restrict__ stats2,
                                               float* __restrict__ out) {
  int b = blockIdx.y, px0 = blockIdx.x * 64, t = threadIdx.x;
  __shared__ float tile[64][68];
  __shared__ float scs[64], shs[64];
  if (t < 64) {
    float S = stats2[(b * 64 + t) * 2], SS = stats2[(b * 64 + t) * 2 + 1];
    float mean = S * (1.0f / (float)HW);
    float var = SS * (1.0f / (float)HW) - mean * mean;
    float rstd = rsqrtf(var + 1e-5f);
    scs[t] = rstd;
    shs[t] = -mean * rstd;
  }
  __syncthreads();
  const unsigned* src = (const unsigned*)(opre + ((size_t)b * HW + px0) * 64);
  for (int i = t; i < 2048; i += 256) {
    int px = i >> 5, q = i & 31;
    unsigned v = src[i];
    int o = q * 2;
    float f0 = bf2f((unsigned short)(v & 0xffff));
    float f1 = bf2f((unsigned short)(v >> 16));
    tile[o][px]     = fmaxf(0.f, fmaf(f0, scs[o], shs[o]));
    tile[o + 1][px] = fmaxf(0.f, fmaf(f1, scs[o + 1], shs[o + 1]));
  }
  __syncthreads();
  for (int j = t; j < 1024; j += 256) {
    int o = j >> 4, w4 = j & 15;
    float4 v = *(const float4*)(&tile[o][w4 * 4]);
    *(float4*)(out + ((size_t)(b * 64) + o) * HW + px0 + w4 * 4) = v;
  }
}

extern "C" void kernel_launch(void* const* d_in, const int* in_sizes, int n_in,
                              void* d_out, int out_size, void* d_ws, size_t ws_size,
                              hipStream_t stream) {
  const float* x  = (const float*)d_in[0];
  const float* W1 = (const float*)d_in[1];
  const float* b1 = (const float*)d_in[2];
  const float* W2 = (const float*)d_in[3];
  const float* b2 = (const float*)d_in[4];
  const float* W3 = (const float*)d_in[5];
  const float* b3 = (const float*)d_in[6];
  float* out = (float*)d_out;

  float* ws = (float*)d_ws;
  float* pooled = ws;                                   // 262144 f
  float* invn   = ws + 262144;                          // 1024 f
  float* stats  = ws + 263168;                          // 4096 f (stats1 | stats2)
  float* stats1 = stats;
  float* stats2 = stats + 2048;
  unsigned short* Mbf  = (unsigned short*)(ws + 267264);   // 262144 us (131072 f)
  unsigned short* W3bf = (unsigned short*)(ws + 398336);   // 20480 us  (10240 f)
  unsigned short* W2bf = (unsigned short*)(ws + 408576);   // 36864 us  (18432 f)
  unsigned short* hpix = (unsigned short*)(ws + 427008);   // 9437184 us (4718592 f)
  float* y0            = ws + 5145600;                     // 9437184 f
  unsigned short* opre = (unsigned short*)(ws + 14582784); // 9437184 us
  // total ws usage: 19301376 floats = 77.2 MB

  k_prep<<<dim3(144), dim3(256), 0, stream>>>(W3, W3bf, W2, W2bf, stats);
  k_pool<<<dim3(BB * CC), dim3(256), 0, stream>>>(x, pooled);
  k_invn<<<dim3(BB), dim3(256), 0, stream>>>(pooled, invn);
  k_M<<<dim3(16, BB), dim3(256), 0, stream>>>(pooled, invn, W1, Mbf);
  k_tg1<<<dim3(144, BB), dim3(256), 0, stream>>>(x, Mbf, W3bf, b1, hpix, y0, stats1);
  k_cg2<<<dim3(48, BB), dim3(256), 0, stream>>>(hpix, stats1, W2bf, b2, y0, W3bf, b3, opre, stats2);
  k_apply<<<dim3(144, BB), dim3(256), 0, stream>>>(opre, stats2, out);
}

// Round 9
// 251.551 us; speedup vs baseline: 1.1172x; 1.1172x over previous
//
#include <hip/hip_runtime.h>

#define BB 16
#define CC 256
#define HW 9216   // 96*96

typedef short bf16x8 __attribute__((ext_vector_type(8)));
typedef float f32x4 __attribute__((ext_vector_type(4)));

__device__ __forceinline__ unsigned short f2bf(float f) {
  unsigned u = __float_as_uint(f);
  return (unsigned short)((u + 0x7FFFu + ((u >> 16) & 1u)) >> 16);
}
__device__ __forceinline__ float bf2f(unsigned short h) {
  return __uint_as_float(((unsigned)h) << 16);
}

// ---------------- K1: adaptive avg pool 96x96 -> 8x8 per (b,c) plane ----------------
__global__ __launch_bounds__(256) void k_pool(const float* __restrict__ x,
                                              float* __restrict__ pooled) {
  int bc = blockIdx.x;
  const float* plane = x + (size_t)bc * HW;
  __shared__ float rowwin[96][8];
  for (int idx = threadIdx.x; idx < 96 * 8; idx += 256) {
    int y = idx >> 3, wx = idx & 7;
    const float* r = plane + y * 96 + wx * 12;
    float s = 0.f;
#pragma unroll
    for (int i = 0; i < 12; ++i) s += r[i];
    rowwin[y][wx] = s;
  }
  __syncthreads();
  if (threadIdx.x < 64) {
    int wy = threadIdx.x >> 3, wx = threadIdx.x & 7;
    float s = 0.f;
#pragma unroll
    for (int i = 0; i < 12; ++i) s += rowwin[wy * 12 + i][wx];
    pooled[(size_t)bc * 64 + threadIdx.x] = s * (1.0f / 144.0f);
  }
}

// ---------------- K2: inverse L2 norm over channels of pooled, per (b,p) ----------------
__global__ __launch_bounds__(256) void k_invn(const float* __restrict__ pooled,
                                              float* __restrict__ invn) {
  int b = blockIdx.x;
  int p = threadIdx.x & 63, cg = threadIdx.x >> 6;
  const float* pb = pooled + (size_t)b * CC * 64;
  float s = 0.f;
  for (int c = cg; c < CC; c += 4) { float v = pb[c * 64 + p]; s += v * v; }
  __shared__ float sm[4][64];
  sm[cg][p] = s;
  __syncthreads();
  if (threadIdx.x < 64) {
    float tot = sm[0][p] + sm[1][p] + sm[2][p] + sm[3][p];
    invn[b * 64 + p] = 1.0f / fmaxf(sqrtf(tot), 1e-12f);
  }
}

// ---------------- K3: Mbf[b][o][c] = bf16( sum_p W1[o][p] * ker[b][c][p] ) ----------------
__global__ __launch_bounds__(256) void k_M(const float* __restrict__ pooled,
                                           const float* __restrict__ invn,
                                           const float* __restrict__ W1,
                                           unsigned short* __restrict__ Mbf) {
  int c0 = blockIdx.x * 16, b = blockIdx.y, t = threadIdx.x;
  __shared__ float W1s[64][65];
  __shared__ float kers[16][65];
  __shared__ float invs[64];
  if (t < 64) invs[t] = invn[b * 64 + t];
  for (int i = t; i < 4096; i += 256) W1s[i >> 6][i & 63] = W1[i];
  __syncthreads();
  for (int i = t; i < 1024; i += 256) {
    int c = i >> 6, p = i & 63;
    kers[c][p] = pooled[((size_t)b * CC + c0 + c) * 64 + p] * invs[p];
  }
  __syncthreads();
  int c = t & 15, og = t >> 4;
  float s0 = 0.f, s1 = 0.f, s2 = 0.f, s3 = 0.f;
#pragma unroll
  for (int p = 0; p < 64; ++p) {
    float kv = kers[c][p];
    s0 = fmaf(W1s[og * 4 + 0][p], kv, s0);
    s1 = fmaf(W1s[og * 4 + 1][p], kv, s1);
    s2 = fmaf(W1s[og * 4 + 2][p], kv, s2);
    s3 = fmaf(W1s[og * 4 + 3][p], kv, s3);
  }
  unsigned short* Mb = Mbf + (size_t)b * 64 * 256 + c0 + c;
  Mb[(og * 4 + 0) * 256] = f2bf(s0);
  Mb[(og * 4 + 1) * 256] = f2bf(s1);
  Mb[(og * 4 + 2) * 256] = f2bf(s2);
  Mb[(og * 4 + 3) * 256] = f2bf(s3);
}

// ---------------- K4: prep: W3 -> bf16 [o][320], W2 -> bf16 [tap][o][f], zero stats ----------------
__global__ void k_prep(const float* __restrict__ W3, unsigned short* __restrict__ W3bf,
                       const float* __restrict__ W2, unsigned short* __restrict__ W2bf,
                       float* __restrict__ statsbuf) {
  int i = blockIdx.x * 256 + threadIdx.x;
  if (i < 64 * 320) W3bf[i] = f2bf(W3[i]);
  if (i < 9 * 64 * 64) {
    int tap = i >> 12, rem = i & 4095;
    int o = rem >> 6, f = rem & 63;
    W2bf[i] = f2bf(W2[(size_t)(o * 64 + f) * 9 + tap]);
  }
  if (i < 4096) statsbuf[i] = 0.f;
}

// ---------------- K5: fused transpose + gemm1 + y0: per (b, 64-px tile) ----------------
__global__ __launch_bounds__(256) void k_tg1(
    const float* __restrict__ x,
    const unsigned short* __restrict__ Mbf,
    const unsigned short* __restrict__ W3bf,
    const float* __restrict__ b1,
    unsigned short* __restrict__ hpix,
    float* __restrict__ y0,
    float* __restrict__ stats1) {
  int b = blockIdx.y;
  int px0 = blockIdx.x * 64;
  int t = threadIdx.x;
  int px = t & 63, cg = t >> 6;            // staging roles
  int w = t >> 6, lane = t & 63, l15 = lane & 15, l4 = lane >> 4;  // MFMA roles
  __shared__ unsigned char sm[32768];      // [64 px][256 c] bf16, 16B-granule swizzled
  __shared__ float sq[64];
  if (t < 64) sq[t] = 0.f;
  __syncthreads();
  // ---- stage ----
  float part = 0.f;
  const float* xb = x + (size_t)b * CC * HW + px0 + px;
#pragma unroll
  for (int kk = 0; kk < 8; ++kk) {
    int c = cg * 64 + kk * 8;
    float v[8];
#pragma unroll
    for (int j = 0; j < 8; ++j) {
      v[j] = xb[(size_t)(c + j) * HW];
      part += v[j] * v[j];
    }
    uint4 pk;
    pk.x = (unsigned)f2bf(v[0]) | ((unsigned)f2bf(v[1]) << 16);
    pk.y = (unsigned)f2bf(v[2]) | ((unsigned)f2bf(v[3]) << 16);
    pk.z = (unsigned)f2bf(v[4]) | ((unsigned)f2bf(v[5]) << 16);
    pk.w = (unsigned)f2bf(v[6]) | ((unsigned)f2bf(v[7]) << 16);
    int u = cg * 8 + kk;
    *(uint4*)(sm + px * 512 + ((u ^ (px & 31)) << 4)) = pk;
  }
  atomicAdd(&sq[px], part);
  __syncthreads();
  // ---- MFMA: wave w owns o-range [w*16, w*16+16) for both h and y0 ----
  f32x4 acch[4], accy[4];
#pragma unroll
  for (int nf = 0; nf < 4; ++nf) { f32x4 z = {0.f,0.f,0.f,0.f}; acch[nf] = z; accy[nf] = z; }
  const unsigned short* Ma = Mbf + ((size_t)b * 64 + w * 16 + l15) * 256;
  const unsigned short* Wa = W3bf + (size_t)(w * 16 + l15) * 320;
#pragma unroll
  for (int kk = 0; kk < 8; ++kk) {
    bf16x8 am = *(const bf16x8*)(Ma + kk * 32 + l4 * 8);
    bf16x8 aw = *(const bf16x8*)(Wa + kk * 32 + l4 * 8);
    int u = kk * 4 + l4;
#pragma unroll
    for (int nf = 0; nf < 4; ++nf) {
      int p2 = nf * 16 + l15;
      bf16x8 bfr = *(const bf16x8*)(sm + p2 * 512 + ((u ^ (p2 & 31)) << 4));
      acch[nf] = __builtin_amdgcn_mfma_f32_16x16x32_bf16(am, bfr, acch[nf], 0, 0, 0);
      accy[nf] = __builtin_amdgcn_mfma_f32_16x16x32_bf16(aw, bfr, accy[nf], 0, 0, 0);
    }
  }
  // ---- epilogue ----
  float inv[4];
#pragma unroll
  for (int nf = 0; nf < 4; ++nf)
    inv[nf] = 1.0f / fmaxf(sqrtf(sq[nf * 16 + l15]), 1e-12f);
  float b1v[4];
#pragma unroll
  for (int i = 0; i < 4; ++i) b1v[i] = b1[w * 16 + l4 * 4 + i];
  float s_acc[4], ss_acc[4];
#pragma unroll
  for (int i = 0; i < 4; ++i) { s_acc[i] = 0.f; ss_acc[i] = 0.f; }
  __syncthreads();                          // all sm MFMA reads done; reuse as h epi tile
#pragma unroll
  for (int nf = 0; nf < 4; ++nf) {
    float hv[4];
#pragma unroll
    for (int i = 0; i < 4; ++i) {
      hv[i] = fmaf(acch[nf][i], inv[nf], b1v[i]);
      s_acc[i] += hv[i];
      ss_acc[i] += hv[i] * hv[i];
    }
    uint2 pk;
    pk.x = (unsigned)f2bf(hv[0]) | ((unsigned)f2bf(hv[1]) << 16);
    pk.y = (unsigned)f2bf(hv[2]) | ((unsigned)f2bf(hv[3]) << 16);
    int p2 = nf * 16 + l15;
    int v = w * 4 + l4;                     // 8B unit (4 o's) within 128B pixel row
    *(uint2*)(sm + p2 * 128 + ((v ^ ((p2 & 7) << 1)) << 3)) = pk;
#pragma unroll
    for (int i = 0; i < 4; ++i)
      y0[((size_t)(b * 64 + w * 16 + l4 * 4 + i)) * HW + px0 + nf * 16 + l15] = accy[nf][i];
  }
#pragma unroll
  for (int i = 0; i < 4; ++i) {
    float s = s_acc[i], q = ss_acc[i];
#pragma unroll
    for (int m = 1; m < 16; m <<= 1) {
      s += __shfl_xor(s, m);
      q += __shfl_xor(q, m);
    }
    if (l15 == 0) {
      int o = w * 16 + l4 * 4 + i;
      atomicAdd(&stats1[(b * 64 + o) * 2], s);
      atomicAdd(&stats1[(b * 64 + o) * 2 + 1], q);
    }
  }
  __syncthreads();
  uint4* dst = (uint4*)(hpix + ((size_t)b * HW + px0) * 64);
  for (int i = t; i < 512; i += 256) {
    int p = i >> 3, u16 = i & 7;
    dst[i] = *(const uint4*)(sm + p * 128 + ((u16 ^ (p & 7)) << 4));
  }
}

// ---------------- K6: hnorm = relu(IN(hpix)) -> row-padded bf16 [b][96pad | HW | 96pad][64] ----------------
__global__ __launch_bounds__(256) void k_hnorm(
    const unsigned short* __restrict__ hpix,
    const float* __restrict__ stats1,
    unsigned short* __restrict__ hp) {
  int b = blockIdx.y, tile = blockIdx.x, t = threadIdx.x;
  __shared__ float scs[64], shs[64];
  if (t < 64) {
    float S = stats1[(b * 64 + t) * 2], SS = stats1[(b * 64 + t) * 2 + 1];
    float mean = S * (1.0f / (float)HW);
    float var = SS * (1.0f / (float)HW) - mean * mean;
    float rstd = rsqrtf(var + 1e-5f);
    scs[t] = rstd;
    shs[t] = -mean * rstd;
  }
  __syncthreads();
  const uint2* src = (const uint2*)(hpix + ((size_t)b * HW + tile * 64) * 64);
  uint2* dst = (uint2*)(hp + ((size_t)b * (HW + 192) + 96 + tile * 64) * 64);
  for (int i = t; i < 1024; i += 256) {
    int u = i & 15;
    int c0 = u * 4;
    uint2 v = src[i];
    float f0 = fmaxf(0.f, fmaf(bf2f((unsigned short)(v.x & 0xffff)), scs[c0],     shs[c0]));
    float f1 = fmaxf(0.f, fmaf(bf2f((unsigned short)(v.x >> 16)),    scs[c0 + 1], shs[c0 + 1]));
    float f2 = fmaxf(0.f, fmaf(bf2f((unsigned short)(v.y & 0xffff)), scs[c0 + 2], shs[c0 + 2]));
    float f3 = fmaxf(0.f, fmaf(bf2f((unsigned short)(v.y >> 16)),    scs[c0 + 3], shs[c0 + 3]));
    uint2 o;
    o.x = (unsigned)f2bf(f0) | ((unsigned)f2bf(f1) << 16);
    o.y = (unsigned)f2bf(f2) | ((unsigned)f2bf(f3) << 16);
    dst[i] = o;
  }
  if (tile == 0) {
    uint2 z; z.x = 0; z.y = 0;
    uint2* p0 = (uint2*)(hp + (size_t)b * (HW + 192) * 64);
    uint2* p1 = (uint2*)(hp + ((size_t)b * (HW + 192) + 96 + HW) * 64);
    for (int i = t; i < 96 * 16; i += 256) { p0[i] = z; p1[i] = z; }
  }
}

// ---------------- K7: conv3x3 as 9 shifted GEMMs (no staging/barriers) + gemm2-lite ----------------
__global__ __launch_bounds__(256) void k_conv9(
    const unsigned short* __restrict__ hp,   // padded hnorm
    const unsigned short* __restrict__ W2bf, // [tap][o][f]
    const float* __restrict__ b2,
    const float* __restrict__ y0,
    const unsigned short* __restrict__ W3bf, // [o][320]
    const float* __restrict__ b3,
    unsigned short* __restrict__ opre,
    float* __restrict__ stats2) {
  int b = blockIdx.y;
  int t = threadIdx.x;
  int w = t >> 6, lane = t & 63, l15 = lane & 15, l4 = lane >> 4;
  int pxw = blockIdx.x * 128 + w * 32;     // wave base pixel; pxw%96 in {0,32,64} -> row-aligned
  int xs = pxw % 96;
  __shared__ unsigned char tlds[16384];    // 4 waves x 32px x 128B (wave-private)
  __shared__ float sb[128];
  unsigned char* wb = tlds + w * 4096;
  if (t < 128) sb[t] = 0.f;

  const unsigned short* hpb = hp + ((size_t)b * (HW + 192) + 96) * 64;

  f32x4 acc[4][2];
#pragma unroll
  for (int mf = 0; mf < 4; ++mf)
#pragma unroll
    for (int nf = 0; nf < 2; ++nf) { f32x4 z = {0.f,0.f,0.f,0.f}; acc[mf][nf] = z; }
  bf16x8 zerov = {0,0,0,0,0,0,0,0};

#pragma unroll
  for (int dy = 0; dy < 3; ++dy)
#pragma unroll
    for (int dx = 0; dx < 3; ++dx) {
      int tap = dy * 3 + dx;
      int doff = (dy - 1) * 96 + (dx - 1);
#pragma unroll
      for (int kk = 0; kk < 2; ++kk) {
        bf16x8 afr[4];
#pragma unroll
        for (int mf = 0; mf < 4; ++mf)
          afr[mf] = *(const bf16x8*)(W2bf + ((size_t)(tap * 64 + mf * 16 + l15)) * 64 + kk * 32 + l4 * 8);
#pragma unroll
        for (int nf = 0; nf < 2; ++nf) {
          int p = pxw + nf * 16 + l15;
          int t0n = xs + nf * 16 + l15;            // lane's x in [0,95]
          bool z = (dx == 0 && t0n == 0) || (dx == 2 && t0n == 95);
          int pidx = z ? p : (p + doff);           // clamp masked lanes in-bounds
          bf16x8 bfr = *(const bf16x8*)(hpb + (size_t)pidx * 64 + kk * 32 + l4 * 8);
          if (z) bfr = zerov;
#pragma unroll
          for (int mf = 0; mf < 4; ++mf)
            acc[mf][nf] = __builtin_amdgcn_mfma_f32_16x16x32_bf16(afr[mf], bfr, acc[mf][nf], 0, 0, 0);
        }
      }
    }
  // ---- hh (+b2) -> wave-private LDS tile [32 px][64 o] (swizzled 8B units) ----
  float b2v[4][4];
#pragma unroll
  for (int mf = 0; mf < 4; ++mf)
#pragma unroll
    for (int i = 0; i < 4; ++i) b2v[mf][i] = b2[mf * 16 + l4 * 4 + i];
#pragma unroll
  for (int mf = 0; mf < 4; ++mf)
#pragma unroll
    for (int nf = 0; nf < 2; ++nf) {
      int lpx = nf * 16 + l15;
      uint2 pk;
      pk.x = (unsigned)f2bf(acc[mf][nf][0] + b2v[mf][0]) |
             ((unsigned)f2bf(acc[mf][nf][1] + b2v[mf][1]) << 16);
      pk.y = (unsigned)f2bf(acc[mf][nf][2] + b2v[mf][2]) |
             ((unsigned)f2bf(acc[mf][nf][3] + b2v[mf][3]) << 16);
      int v = mf * 4 + l4;
      *(uint2*)(wb + lpx * 128 + ((v ^ ((lpx & 7) << 1)) << 3)) = pk;
    }
  __syncthreads();
  // ---- gemm2-lite: acc2 = y0 + W3[:,256:]·hh ----
  f32x4 acc2[4][2];
#pragma unroll
  for (int mf = 0; mf < 4; ++mf)
#pragma unroll
    for (int i = 0; i < 4; ++i) {
      const float* yr = y0 + ((size_t)(b * 64 + mf * 16 + l4 * 4 + i)) * HW + pxw + l15;
#pragma unroll
      for (int nf = 0; nf < 2; ++nf) acc2[mf][nf][i] = yr[nf * 16];
    }
#pragma unroll
  for (int kk = 0; kk < 2; ++kk) {
    bf16x8 afr[4];
#pragma unroll
    for (int mf = 0; mf < 4; ++mf)
      afr[mf] = *(const bf16x8*)(W3bf + (size_t)(mf * 16 + l15) * 320 + 256 + kk * 32 + l4 * 8);
#pragma unroll
    for (int nf = 0; nf < 2; ++nf) {
      int lpx = nf * 16 + l15;
      int v0 = kk * 8 + l4 * 2;
      union { bf16x8 v; uint2 h[2]; } bb;
      bb.h[0] = *(const uint2*)(wb + lpx * 128 + (((v0    ) ^ ((lpx & 7) << 1)) << 3));
      bb.h[1] = *(const uint2*)(wb + lpx * 128 + (((v0 + 1) ^ ((lpx & 7) << 1)) << 3));
#pragma unroll
      for (int mf = 0; mf < 4; ++mf)
        acc2[mf][nf] = __builtin_amdgcn_mfma_f32_16x16x32_bf16(afr[mf], bb.v, acc2[mf][nf], 0, 0, 0);
    }
  }
  // ---- stats2 (block-LDS reduce, then 64 global atomics) ----
  float b3v[4][4];
#pragma unroll
  for (int mf = 0; mf < 4; ++mf)
#pragma unroll
    for (int i = 0; i < 4; ++i) b3v[mf][i] = b3[mf * 16 + l4 * 4 + i];
#pragma unroll
  for (int mf = 0; mf < 4; ++mf)
#pragma unroll
    for (int i = 0; i < 4; ++i) {
      float s = 0.f, q = 0.f;
#pragma unroll
      for (int nf = 0; nf < 2; ++nf) {
        float hv = acc2[mf][nf][i] + b3v[mf][i];
        s += hv;
        q += hv * hv;
      }
#pragma unroll
      for (int m = 1; m < 16; m <<= 1) {
        s += __shfl_xor(s, m);
        q += __shfl_xor(q, m);
      }
      if (l15 == 0) {
        int o = mf * 16 + l4 * 4 + i;
        atomicAdd(&sb[o * 2], s);
        atomicAdd(&sb[o * 2 + 1], q);
      }
    }
  __syncthreads();
  if (t < 64) {
    atomicAdd(&stats2[(b * 64 + t) * 2], sb[t * 2]);
    atomicAdd(&stats2[(b * 64 + t) * 2 + 1], sb[t * 2 + 1]);
  }
  // ---- opre bf16 pixel-major direct stores (8B per lane per (mf,nf)) ----
#pragma unroll
  for (int mf = 0; mf < 4; ++mf)
#pragma unroll
    for (int nf = 0; nf < 2; ++nf) {
      int p = pxw + nf * 16 + l15;
      uint2 pk;
      pk.x = (unsigned)f2bf(acc2[mf][nf][0] + b3v[mf][0]) |
             ((unsigned)f2bf(acc2[mf][nf][1] + b3v[mf][1]) << 16);
      pk.y = (unsigned)f2bf(acc2[mf][nf][2] + b3v[mf][2]) |
             ((unsigned)f2bf(acc2[mf][nf][3] + b3v[mf][3]) << 16);
      *(uint2*)(opre + ((size_t)b * HW + p) * 64 + mf * 16 + l4 * 4) = pk;
    }
}

// ---------------- K8: apply IN+ReLU, transpose to o-major fp32 d_out ----------------
__global__ __launch_bounds__(256) void k_apply(const unsigned short* __restrict__ opre,
                                               const float* __restrict__ stats2,
                                               float* __restrict__ out) {
  int b = blockIdx.y, px0 = blockIdx.x * 64, t = threadIdx.x;
  __shared__ float tile[64][68];
  __shared__ float scs[64], shs[64];
  if (t < 64) {
    float S = stats2[(b * 64 + t) * 2], SS = stats2[(b * 64 + t) * 2 + 1];
    float mean = S * (1.0f / (float)HW);
    float var = SS * (1.0f / (float)HW) - mean * mean;
    float rstd = rsqrtf(var + 1e-5f);
    scs[t] = rstd;
    shs[t] = -mean * rstd;
  }
  __syncthreads();
  const unsigned* src = (const unsigned*)(opre + ((size_t)b * HW + px0) * 64);
  for (int i = t; i < 2048; i += 256) {
    int px = i >> 5, q = i & 31;
    unsigned v = src[i];
    int o = q * 2;
    float f0 = bf2f((unsigned short)(v & 0xffff));
    float f1 = bf2f((unsigned short)(v >> 16));
    tile[o][px]     = fmaxf(0.f, fmaf(f0, scs[o], shs[o]));
    tile[o + 1][px] = fmaxf(0.f, fmaf(f1, scs[o + 1], shs[o + 1]));
  }
  __syncthreads();
  for (int j = t; j < 1024; j += 256) {
    int o = j >> 4, w4 = j & 15;
    float4 v = *(const float4*)(&tile[o][w4 * 4]);
    *(float4*)(out + ((size_t)(b * 64) + o) * HW + px0 + w4 * 4) = v;
  }
}

extern "C" void kernel_launch(void* const* d_in, const int* in_sizes, int n_in,
                              void* d_out, int out_size, void* d_ws, size_t ws_size,
                              hipStream_t stream) {
  const float* x  = (const float*)d_in[0];
  const float* W1 = (const float*)d_in[1];
  const float* b1 = (const float*)d_in[2];
  const float* W2 = (const float*)d_in[3];
  const float* b2 = (const float*)d_in[4];
  const float* W3 = (const float*)d_in[5];
  const float* b3 = (const float*)d_in[6];
  float* out = (float*)d_out;

  float* ws = (float*)d_ws;
  float* pooled = ws;                                   // 262144 f
  float* invn   = ws + 262144;                          // 1024 f
  float* stats  = ws + 263168;                          // 4096 f (stats1 | stats2)
  float* stats1 = stats;
  float* stats2 = stats + 2048;
  unsigned short* Mbf  = (unsigned short*)(ws + 267264);   // 262144 us (131072 f)
  unsigned short* W3bf = (unsigned short*)(ws + 398336);   // 20480 us  (10240 f)
  unsigned short* W2bf = (unsigned short*)(ws + 408576);   // 36864 us  (18432 f)
  unsigned short* hpix = (unsigned short*)(ws + 427008);   // 9437184 us (4718592 f)
  float* y0            = ws + 5145600;                     // 9437184 f
  unsigned short* opre = (unsigned short*)(ws + 14582784); // 9437184 us (4718592 f)
  unsigned short* hp   = (unsigned short*)(ws + 19301376); // 16*9408*64 us = 9633792 us (4816896 f)
  // end: 24118272 f = 96.5 MB (<= R4's 96.7 MB usage)

  k_prep<<<dim3(144), dim3(256), 0, stream>>>(W3, W3bf, W2, W2bf, stats);
  k_pool<<<dim3(BB * CC), dim3(256), 0, stream>>>(x, pooled);
  k_invn<<<dim3(BB), dim3(256), 0, stream>>>(pooled, invn);
  k_M<<<dim3(16, BB), dim3(256), 0, stream>>>(pooled, invn, W1, Mbf);
  k_tg1<<<dim3(144, BB), dim3(256), 0, stream>>>(x, Mbf, W3bf, b1, hpix, y0, stats1);
  k_hnorm<<<dim3(144, BB), dim3(256), 0, stream>>>(hpix, stats1, hp);
  k_conv9<<<dim3(72, BB), dim3(256), 0, stream>>>(hp, W2bf, b2, y0, W3bf, b3, opre, stats2);
  k_apply<<<dim3(144, BB), dim3(256), 0, stream>>>(opre, stats2, out);
}